// Round 1
// baseline (627.520 us; speedup 1.0000x reference)
//
#include <hip/hip_runtime.h>
#include <cstddef>

#define GEMM_K 512
#define GEMM_N 1024

typedef __attribute__((ext_vector_type(4))) float f4;

// EC[m][n] for m in [0,2560): rows 0..2047 = enc@W^T + bias, rows 2048..2559 = dec@W^T
// grid (2560/64=40, 1024/128=8), block 256
__global__ __launch_bounds__(256) void gemm_joint(
    const float* __restrict__ enc,   // [2048][512]
    const float* __restrict__ dec,   // [512][512]
    const float* __restrict__ W,     // [1024][512]
    const float* __restrict__ bias,  // [1024]
    float* __restrict__ EC)          // [2560][1024]
{
    __shared__ float As[64 * 32];    // row m: element k at pos (k ^ ((m>>3)<<2))
    __shared__ float Ws[128 * 32];   // row n: element k at pos (k ^ (((n>>3)&7)<<2))

    const int tid = threadIdx.x;
    const int m0 = blockIdx.x * 64;
    const int n0 = blockIdx.y * 128;
    const bool is_enc = (m0 < 2048);
    const float* __restrict__ Abase =
        is_enc ? (enc + (size_t)m0 * GEMM_K) : (dec + (size_t)(m0 - 2048) * GEMM_K);

    const int tx = tid & 15;   // 16 column groups x 8 cols
    const int ty = tid >> 4;   // 16 row groups x 4 rows

    float acc[4][8];
#pragma unroll
    for (int i = 0; i < 4; ++i)
#pragma unroll
        for (int j = 0; j < 8; ++j) acc[i][j] = 0.f;

    const int ar = tid >> 3;   // 0..31
    const int ak = tid & 7;    // k-quad 0..7

    float4 ra[2], rw[4];
    // first tile (k0 = 0)
    {
        const float* ap = Abase + (size_t)ar * GEMM_K + (ak << 2);
        ra[0] = *(const float4*)(ap);
        ra[1] = *(const float4*)(ap + 32 * GEMM_K);
        const float* wp = W + (size_t)(n0 + ar) * GEMM_K + (ak << 2);
        rw[0] = *(const float4*)(wp);
        rw[1] = *(const float4*)(wp + 32 * GEMM_K);
        rw[2] = *(const float4*)(wp + 64 * GEMM_K);
        rw[3] = *(const float4*)(wp + 96 * GEMM_K);
    }

    for (int k0 = 0; k0 < GEMM_K; k0 += 32) {
        // stage registers -> LDS (XOR quad swizzle keeps 16B alignment)
        {
            const int r0 = ar, r1 = ar + 32;
            const int q0 = (ak ^ (r0 >> 3)) & 7;
            const int q1 = (ak ^ (r1 >> 3)) & 7;
            *(float4*)(&As[r0 * 32 + q0 * 4]) = ra[0];
            *(float4*)(&As[r1 * 32 + q1 * 4]) = ra[1];
#pragma unroll
            for (int i = 0; i < 4; ++i) {
                const int r = ar + 32 * i;
                const int q = (ak ^ (r >> 3)) & 7;
                *(float4*)(&Ws[r * 32 + q * 4]) = rw[i];
            }
        }
        __syncthreads();

        // prefetch next tile while computing this one
        if (k0 + 32 < GEMM_K) {
            const float* ap = Abase + (size_t)ar * GEMM_K + (k0 + 32) + (ak << 2);
            ra[0] = *(const float4*)(ap);
            ra[1] = *(const float4*)(ap + 32 * GEMM_K);
            const float* wp = W + (size_t)(n0 + ar) * GEMM_K + (k0 + 32) + (ak << 2);
            rw[0] = *(const float4*)(wp);
            rw[1] = *(const float4*)(wp + 32 * GEMM_K);
            rw[2] = *(const float4*)(wp + 64 * GEMM_K);
            rw[3] = *(const float4*)(wp + 96 * GEMM_K);
        }

#pragma unroll 8
        for (int kk = 0; kk < 32; ++kk) {
            float a[4], b[8];
#pragma unroll
            for (int i = 0; i < 4; ++i) {
                const int m = ty * 4 + i;
                a[i] = As[m * 32 + (kk ^ ((m >> 3) << 2))];
            }
#pragma unroll
            for (int j = 0; j < 8; ++j) {
                const int n = tx * 8 + j;
                b[j] = Ws[n * 32 + (kk ^ (((n >> 3) & 7) << 2))];
            }
#pragma unroll
            for (int i = 0; i < 4; ++i)
#pragma unroll
                for (int j = 0; j < 8; ++j) acc[i][j] = fmaf(a[i], b[j], acc[i][j]);
        }
        __syncthreads();
    }

    // epilogue: + bias (enc rows only; bias must appear exactly once in final sum)
    float4 bia = make_float4(0.f, 0.f, 0.f, 0.f);
    float4 bib = make_float4(0.f, 0.f, 0.f, 0.f);
    if (is_enc) {
        bia = *(const float4*)(bias + n0 + tx * 8);
        bib = *(const float4*)(bias + n0 + tx * 8 + 4);
    }
#pragma unroll
    for (int i = 0; i < 4; ++i) {
        const int m = m0 + ty * 4 + i;
        float4 c0 = make_float4(acc[i][0] + bia.x, acc[i][1] + bia.y,
                                acc[i][2] + bia.z, acc[i][3] + bia.w);
        float4 c1 = make_float4(acc[i][4] + bib.x, acc[i][5] + bib.y,
                                acc[i][6] + bib.z, acc[i][7] + bib.w);
        float* crow = EC + (size_t)m * GEMM_N + n0 + tx * 8;
        *(float4*)(crow) = c0;
        *(float4*)(crow + 4) = c1;
    }
}

// out[(bt*64+u)*1024 + v] = E[bt][v] + Dm[b*64+u][v]
// grid 2048 blocks (one per bt), block 256; each thread owns one float4 of the V-row
__global__ __launch_bounds__(256) void bcast_add(
    const float* __restrict__ EC, float* __restrict__ out)
{
    const int bt = blockIdx.x;        // 0..2047
    const int b = bt >> 8;            // batch 0..7
    const int tid = threadIdx.x;

    const f4 e = ((const f4*)(EC + (size_t)bt * 1024))[tid];
    const f4* __restrict__ dbase = (const f4*)(EC + (size_t)(2048 + b * 64) * 1024);
    f4* __restrict__ obase = (f4*)(out + (size_t)bt * 64 * 1024);

#pragma unroll 4
    for (int u = 0; u < 64; ++u) {
        f4 d = dbase[u * 256 + tid];
        f4 o = e + d;
        __builtin_nontemporal_store(o, &obase[u * 256 + tid]);
    }
}

extern "C" void kernel_launch(void* const* d_in, const int* in_sizes, int n_in,
                              void* d_out, int out_size, void* d_ws, size_t ws_size,
                              hipStream_t stream) {
    const float* enc  = (const float*)d_in[0];  // 8*256*512
    const float* dec  = (const float*)d_in[1];  // 8*64*512
    const float* W    = (const float*)d_in[2];  // 1024*512
    const float* bias = (const float*)d_in[3];  // 1024
    float* out = (float*)d_out;                 // 8*256*64*1024
    float* EC = (float*)d_ws;                   // 2560*1024 floats = 10 MiB

    dim3 g1(40, 8);
    gemm_joint<<<g1, dim3(256), 0, stream>>>(enc, dec, W, bias, EC);
    bcast_add<<<2048, 256, 0, stream>>>(EC, out);
}